// Round 10
// baseline (159.827 us; speedup 1.0000x reference)
//
#include <hip/hip_runtime.h>

#define DEVI __device__ __forceinline__

typedef __attribute__((ext_vector_type(8))) short short8x;
typedef __attribute__((ext_vector_type(4))) float float4x;

DEVI float shx(float v, int m) { return __shfl_xor(v, m, 64); }

DEVI unsigned bf16r(float v) {
  unsigned u = __float_as_uint(v);
  return (u + 0x7FFF + ((u >> 16) & 1)) >> 16;
}
// split two floats into packed bf16 hi-pair and lo-pair (RNE both levels)
DEVI void split2(float a, float b, unsigned& h, unsigned& l) {
  unsigned ra = bf16r(a), rb = bf16r(b);
  float fa = __uint_as_float(ra << 16), fb = __uint_as_float(rb << 16);
  unsigned la = bf16r(a - fa), lb = bf16r(b - fb);
  h = ra | (rb << 16);
  l = la | (lb << 16);
}

// async global->LDS, 16B per lane; LDS dest = wave-uniform base + lane*16
DEVI void gload16(const void* g, void* l) {
  __builtin_amdgcn_global_load_lds(
      (const __attribute__((address_space(1))) void*)g,
      (__attribute__((address_space(3))) void*)l, 16, 0, 0);
}

// Cross-lane xor-exchange. mask 1/2 -> DPP quad_perm; mask 4/8 -> ds_swizzle.
template <int MASK>
DEVI float lanex(float x) {
  if constexpr (MASK == 1)
    return __int_as_float(__builtin_amdgcn_update_dpp(
        0, __float_as_int(x), 0xB1, 0xF, 0xF, true));
  else if constexpr (MASK == 2)
    return __int_as_float(__builtin_amdgcn_update_dpp(
        0, __float_as_int(x), 0x4E, 0xF, 0xF, true));
  else
    return __int_as_float(__builtin_amdgcn_ds_swizzle(
        __float_as_int(x), (MASK << 10) | 0x1F));
}

// ---------------------------------------------------------- fused conv1+conv2
// Hadamard "conv" == 9-tap XOR-translate stencil:
//   out[i,j] = (1/n) * sum_{r,c<3} w[r,c] * S[i^r, j^c]
// Blocks >= B perform the fc1_w fp32 -> bf16 hi/lo split (merged k_wsplit).
__global__ __launch_bounds__(256) void k_conv(
    const float* __restrict__ x, const float* __restrict__ filt1,
    const float* __restrict__ bias1, const float* __restrict__ filt2,
    const float* __restrict__ bias2, unsigned short* __restrict__ Ah,
    unsigned short* __restrict__ Al, const float* __restrict__ fc1w,
    unsigned short* __restrict__ Wh, unsigned short* __restrict__ Wl, int B) {
  __shared__ float sP[4 * 320];  // 4 waves x 16 rows x stride 20
  const int b = blockIdx.x;
  const int tid = threadIdx.x;

  if (b >= B) {  // ---- merged W-split: 512 blocks x 4096 floats
    const int wb = b - B;
#pragma unroll
    for (int q = 0; q < 4; ++q) {
      const int i = wb * 4096 + q * 1024 + tid * 4;
      float4 v = *(const float4*)(fc1w + i);
      unsigned h0, l0, h1, l1;
      split2(v.x, v.y, h0, l0);
      split2(v.z, v.w, h1, l1);
      *(uint2*)(Wh + i) = make_uint2(h0, h1);
      *(uint2*)(Wl + i) = make_uint2(l0, l1);
    }
    return;
  }

  const int wv = tid >> 6, t = tid & 63;

  // ---- S = (1/32) * sum_c x[b,c], own row per lane
  float s0[16];
  {
    const float* xb = x + (size_t)b * 3072 + (t >> 1) * 32 + (t & 1) * 16;
#pragma unroll
    for (int q = 0; q < 4; ++q) {
      float4 a0 = *(const float4*)(xb + 4 * q);
      float4 a1 = *(const float4*)(xb + 1024 + 4 * q);
      float4 a2 = *(const float4*)(xb + 2048 + 4 * q);
      s0[4 * q + 0] = (a0.x + a1.x + a2.x) * (1.0f / 32.0f);
      s0[4 * q + 1] = (a0.y + a1.y + a2.y) * (1.0f / 32.0f);
      s0[4 * q + 2] = (a0.z + a1.z + a2.z) * (1.0f / 32.0f);
      s0[4 * q + 3] = (a0.w + a1.w + a2.w) * (1.0f / 32.0f);
    }
  }
  // hoisted xor-row sets (shared across all 8 filters)
  float s1[16], s2[16];
#pragma unroll
  for (int k = 0; k < 16; ++k) s1[k] = lanex<2>(s0[k]);
#pragma unroll
  for (int k = 0; k < 16; ++k) s2[k] = lanex<4>(s0[k]);

  float acc[8];
#pragma unroll
  for (int j = 0; j < 8; ++j) acc[j] = 0.0f;

  // ---- conv1: 8 filters per wave, 9-tap stencil each
  for (int i = 0; i < 8; ++i) {
    const int f = __builtin_amdgcn_readfirstlane(wv * 8 + i);
    const float* fp = filt1 + f * 9;
    float w[9];
#pragma unroll
    for (int k = 0; k < 9; ++k) w[k] = fp[k];
    const float bb = bias1[f];
    float c[8];
#pragma unroll
    for (int p = 0; p < 8; ++p) {
      const int ja = 2 * p, jb = ja ^ 1;
      const int ja2 = ja ^ 2, jb2 = jb ^ 2;
      float va = fmaf(w[0], s0[ja], bb);
      va = fmaf(w[1], s0[jb], va);
      va = fmaf(w[2], s0[ja2], va);
      va = fmaf(w[3], s1[ja], va);
      va = fmaf(w[4], s1[jb], va);
      va = fmaf(w[5], s1[ja2], va);
      va = fmaf(w[6], s2[ja], va);
      va = fmaf(w[7], s2[jb], va);
      va = fmaf(w[8], s2[ja2], va);
      float vb = fmaf(w[0], s0[jb], bb);
      vb = fmaf(w[1], s0[ja], vb);
      vb = fmaf(w[2], s0[jb2], vb);
      vb = fmaf(w[3], s1[jb], vb);
      vb = fmaf(w[4], s1[ja], vb);
      vb = fmaf(w[5], s1[jb2], vb);
      vb = fmaf(w[6], s2[jb], vb);
      vb = fmaf(w[7], s2[ja], vb);
      vb = fmaf(w[8], s2[jb2], vb);
      c[p] = fmaxf(fmaxf(va, vb), 0.0f);  // col-pair max + relu (v_max3)
    }
    // row pool: partner lane t^2; then accumulate channel-sum S2
#pragma unroll
    for (int p = 0; p < 8; ++p) acc[p] += fmaxf(c[p], lanex<2>(c[p]));
  }

  // ---- per-wave partial S2 (16x16) -> LDS (stride 20)
  if (!(t & 2)) {
    const int pb = wv * 320 + (t >> 2) * 20 + (t & 1) * 8;
    *(float4*)&sP[pb] = make_float4(acc[0], acc[1], acc[2], acc[3]);
    *(float4*)&sP[pb + 4] = make_float4(acc[4], acc[5], acc[6], acc[7]);
  }
  __syncthreads();

  // ---- conv2: assemble S2 row rr (scaled 1/16), 4 its of 4-filter slots
  const int f2s = t >> 4, rr = t & 15;
  float r0[16];
#pragma unroll
  for (int q = 0; q < 4; ++q) {
    float4 s = make_float4(0.f, 0.f, 0.f, 0.f);
#pragma unroll
    for (int w2 = 0; w2 < 4; ++w2) {
      const float4 v = *(const float4*)&sP[w2 * 320 + rr * 20 + 4 * q];
      s.x += v.x; s.y += v.y; s.z += v.z; s.w += v.w;
    }
    r0[4 * q + 0] = s.x * (1.0f / 16.0f);
    r0[4 * q + 1] = s.y * (1.0f / 16.0f);
    r0[4 * q + 2] = s.z * (1.0f / 16.0f);
    r0[4 * q + 3] = s.w * (1.0f / 16.0f);
  }
  float r1[16], r2[16];
#pragma unroll
  for (int k = 0; k < 16; ++k) r1[k] = lanex<1>(r0[k]);
#pragma unroll
  for (int k = 0; k < 16; ++k) r2[k] = lanex<2>(r0[k]);

#pragma unroll
  for (int it = 0; it < 4; ++it) {
    const int g = wv * 16 + it * 4 + f2s;
    const float* gp = filt2 + g * 9;
    float w[9];
#pragma unroll
    for (int k = 0; k < 9; ++k) w[k] = gp[k];
    const float bb = bias2[g];
    float c[8];
#pragma unroll
    for (int p = 0; p < 8; ++p) {
      const int ja = 2 * p, jb = ja ^ 1;
      const int ja2 = ja ^ 2, jb2 = jb ^ 2;
      float va = fmaf(w[0], r0[ja], bb);
      va = fmaf(w[1], r0[jb], va);
      va = fmaf(w[2], r0[ja2], va);
      va = fmaf(w[3], r1[ja], va);
      va = fmaf(w[4], r1[jb], va);
      va = fmaf(w[5], r1[ja2], va);
      va = fmaf(w[6], r2[ja], va);
      va = fmaf(w[7], r2[jb], va);
      va = fmaf(w[8], r2[ja2], va);
      float vb = fmaf(w[0], r0[jb], bb);
      vb = fmaf(w[1], r0[ja], vb);
      vb = fmaf(w[2], r0[jb2], vb);
      vb = fmaf(w[3], r1[jb], vb);
      vb = fmaf(w[4], r1[ja], vb);
      vb = fmaf(w[5], r1[jb2], vb);
      vb = fmaf(w[6], r2[jb], vb);
      vb = fmaf(w[7], r2[ja], vb);
      vb = fmaf(w[8], r2[jb2], vb);
      c[p] = fmaxf(fmaxf(va, vb), 0.0f);
    }
    // row pool: partner lane t^1 (rows rr, rr^1)
#pragma unroll
    for (int p = 0; p < 8; ++p) c[p] = fmaxf(c[p], lanex<1>(c[p]));
    if (!(t & 1)) {
      unsigned hh[4], ll[4];
#pragma unroll
      for (int j = 0; j < 4; ++j) split2(c[2 * j], c[2 * j + 1], hh[j], ll[j]);
      const size_t off = (size_t)b * 4096 + g * 64 + (rr >> 1) * 8;
      *(uint4*)(Ah + off) = make_uint4(hh[0], hh[1], hh[2], hh[3]);
      *(uint4*)(Al + off) = make_uint4(ll[0], ll[1], ll[2], ll[3]);
    }
  }
}

// ------------------------------------------------------------------- FC1
// Split-bf16 MFMA GEMM, BM=64 BN=64 BK=32, split-K=4, depth-3 LDS ring
// (3 x 16 KB) with counted vmcnt (T4): stage(t+2) issued at iter t; end-of-
// iter wait = vmcnt(4) lgkmcnt(0) + raw s_barrier -> stage(t+2)'s 4 loads
// stay in flight across the barrier; loads get 2 iterations to land.
// Grid 1024: bid = c + 128*nt -> bid%8 = c%8, so all 8 nt-blocks sharing an
// A-tile land on one XCD (A working set ~3MB fits 4MB L2).
// LDS row = 128B = 8 chunks {hi k0..k3, lo k0..k3}; involution p^=(r&7) on
// the global source (per-lane addr) and the ds_read; LDS stays linear.
__global__ __launch_bounds__(256) void k_fc1(
    const unsigned short* __restrict__ Ah, const unsigned short* __restrict__ Al,
    const unsigned short* __restrict__ Wh, const unsigned short* __restrict__ Wl,
    float* __restrict__ P, int M) {
  // per buffer: A 64 rows x 128B = 8KB at +0, W 64 rows x 128B = 8KB at +8K
  __shared__ __align__(16) unsigned char lds[49152];  // 3 x 16384
  const int bid = blockIdx.x;
  const int c = bid & 127, nt = bid >> 7;  // bid = c + 128*nt
  const int mt = c >> 2, kidx = c & 3;
  const int m0 = mt * 64, n0 = nt * 64, k0 = kidx * 1024;

  const int tid = threadIdx.x;
  const int wv = tid >> 6, lane = tid & 63;
  const int wm = (wv >> 1) * 32, wn = (wv & 1) * 32;
  const int lm = lane & 15, lq = lane >> 4;
  const int rj = lane >> 3, pj = lane & 7;  // staging: row-in-issue, chunk

  float4x acc[2][2];
#pragma unroll
  for (int i = 0; i < 2; ++i)
#pragma unroll
    for (int j = 0; j < 2; ++j) acc[i][j] = (float4x){0.f, 0.f, 0.f, 0.f};

  // stage K-step st into ring buffer at byte base bb (4 loads per wave)
  auto stage = [&](int st, int bb) {
    const int kcol = k0 + st * 32;
#pragma unroll
    for (int it = 0; it < 2; ++it) {  // A: 16 rows per wave
      const int rb = wv * 16 + it * 8;
      const int r = rb + rj;
      const int l = pj ^ (r & 7);
      const unsigned short* src = (l < 4) ? Ah : Al;
      const size_t go = (size_t)(m0 + r) * 4096 + kcol + (l & 3) * 8;
      gload16(src + go, lds + bb + rb * 128);
    }
#pragma unroll
    for (int it = 0; it < 2; ++it) {  // W: 16 rows per wave
      const int rb = wv * 16 + it * 8;
      const int r = rb + rj;
      const int l = pj ^ (r & 7);
      const unsigned short* src = (l < 4) ? Wh : Wl;
      const size_t go = (size_t)(n0 + r) * 4096 + kcol + (l & 3) * 8;
      gload16(src + go, lds + bb + 8192 + rb * 128);
    }
  };

  stage(0, 0);
  stage(1, 16384);
  asm volatile("s_waitcnt vmcnt(4) lgkmcnt(0)" ::: "memory");
  __builtin_amdgcn_sched_barrier(0);
  __builtin_amdgcn_s_barrier();
  __builtin_amdgcn_sched_barrier(0);

  for (int st = 0; st < 32; ++st) {
    const int bb = (st % 3) * 16384;
    if (st < 30) {
      stage(st + 2, ((st + 2) % 3) * 16384);
      __builtin_amdgcn_sched_barrier(0);
    }

    short8x a_h[2], a_l[2], b_h[2], b_l[2];
#pragma unroll
    for (int fm = 0; fm < 2; ++fm) {
      const int r = wm + fm * 16 + lm;
      const unsigned char* base = lds + bb + r * 128;
      a_h[fm] = *(const short8x*)(base + (lq ^ (r & 7)) * 16);
      a_l[fm] = *(const short8x*)(base + ((lq ^ 4) ^ (r & 7)) * 16);
    }
#pragma unroll
    for (int fn = 0; fn < 2; ++fn) {
      const int r = wn + fn * 16 + lm;
      const unsigned char* base = lds + bb + 8192 + r * 128;
      b_h[fn] = *(const short8x*)(base + (lq ^ (r & 7)) * 16);
      b_l[fn] = *(const short8x*)(base + ((lq ^ 4) ^ (r & 7)) * 16);
    }
#pragma unroll
    for (int fm = 0; fm < 2; ++fm)
#pragma unroll
      for (int fn = 0; fn < 2; ++fn) {
        acc[fm][fn] = __builtin_amdgcn_mfma_f32_16x16x32_bf16(
            a_h[fm], b_h[fn], acc[fm][fn], 0, 0, 0);
        acc[fm][fn] = __builtin_amdgcn_mfma_f32_16x16x32_bf16(
            a_h[fm], b_l[fn], acc[fm][fn], 0, 0, 0);
        acc[fm][fn] = __builtin_amdgcn_mfma_f32_16x16x32_bf16(
            a_l[fm], b_h[fn], acc[fm][fn], 0, 0, 0);
      }

    if (st < 31) {
      // stage(st+1) must be complete for next iter; stage(st+2)'s 4 loads
      // stay in flight (counted vmcnt). lgkmcnt(0): this wave's ds_reads
      // retired before others' DMA writes can touch the ring.
      if (st < 29)
        asm volatile("s_waitcnt vmcnt(4) lgkmcnt(0)" ::: "memory");
      else
        asm volatile("s_waitcnt vmcnt(0) lgkmcnt(0)" ::: "memory");
      __builtin_amdgcn_sched_barrier(0);
      __builtin_amdgcn_s_barrier();
      __builtin_amdgcn_sched_barrier(0);
    }
  }

  float* Pp = P + (size_t)kidx * ((size_t)M * 512);
#pragma unroll
  for (int fm = 0; fm < 2; ++fm)
#pragma unroll
    for (int fn = 0; fn < 2; ++fn)
#pragma unroll
      for (int i = 0; i < 4; ++i) {
        const int r = m0 + wm + fm * 16 + lq * 4 + i;
        const int cc = n0 + wn + fn * 16 + lm;
        Pp[(size_t)r * 512 + cc] = acc[fm][fn][i];
      }
}

// --------------------------------------- FC2 (+ fused split-K red + softmax)
__global__ __launch_bounds__(256) void k_fc2(
    const float* __restrict__ P, const float* __restrict__ bias1,
    const float* __restrict__ W, const float* __restrict__ bias2,
    float* __restrict__ out, int M) {
  const int wv = threadIdx.x >> 6, t = threadIdx.x & 63;
  const int b = blockIdx.x * 4 + wv;
  const size_t ks = (size_t)M * 512;
  const float* pr = P + (size_t)b * 512 + t * 8;
  float4 u0 = *(const float4*)pr;
  float4 u1 = *(const float4*)(pr + 4);
#pragma unroll
  for (int k = 1; k < 4; ++k) {
    const float4 v0 = *(const float4*)(pr + k * ks);
    const float4 v1 = *(const float4*)(pr + k * ks + 4);
    u0.x += v0.x; u0.y += v0.y; u0.z += v0.z; u0.w += v0.w;
    u1.x += v1.x; u1.y += v1.y; u1.z += v1.z; u1.w += v1.w;
  }
  const float4 bb0 = *(const float4*)(bias1 + t * 8);
  const float4 bb1 = *(const float4*)(bias1 + t * 8 + 4);
  float a[8];
  a[0] = fmaxf(u0.x + bb0.x, 0.0f);
  a[1] = fmaxf(u0.y + bb0.y, 0.0f);
  a[2] = fmaxf(u0.z + bb0.z, 0.0f);
  a[3] = fmaxf(u0.w + bb0.w, 0.0f);
  a[4] = fmaxf(u1.x + bb1.x, 0.0f);
  a[5] = fmaxf(u1.y + bb1.y, 0.0f);
  a[6] = fmaxf(u1.z + bb1.z, 0.0f);
  a[7] = fmaxf(u1.w + bb1.w, 0.0f);
  float z[10];
#pragma unroll
  for (int o = 0; o < 10; ++o) {
    const float* wr = W + o * 512 + t * 8;
    const float4 w0 = *(const float4*)wr;
    const float4 w1 = *(const float4*)(wr + 4);
    float s = a[0] * w0.x;
    s = fmaf(a[1], w0.y, s);
    s = fmaf(a[2], w0.z, s);
    s = fmaf(a[3], w0.w, s);
    s = fmaf(a[4], w1.x, s);
    s = fmaf(a[5], w1.y, s);
    s = fmaf(a[6], w1.z, s);
    s = fmaf(a[7], w1.w, s);
    z[o] = s;
  }
#pragma unroll
  for (int m = 1; m < 64; m <<= 1) {
#pragma unroll
    for (int o = 0; o < 10; ++o) z[o] += shx(z[o], m);
  }
#pragma unroll
  for (int o = 0; o < 10; ++o) z[o] += bias2[o];
  float mx = z[0];
#pragma unroll
  for (int o = 1; o < 10; ++o) mx = fmaxf(mx, z[o]);
  float e[10];
  float ssum = 0.0f;
#pragma unroll
  for (int o = 0; o < 10; ++o) {
    e[o] = expf(z[o] - mx);
    ssum += e[o];
  }
  const float inv = 1.0f / ssum;
  if (t == 0) {
    float* dst = out + (size_t)b * 10;
#pragma unroll
    for (int o = 0; o < 10; ++o) dst[o] = e[o] * inv;
  }
}

// ------------------------------------------------------------------ launch
extern "C" void kernel_launch(void* const* d_in, const int* in_sizes, int n_in,
                              void* d_out, int out_size, void* d_ws,
                              size_t ws_size, hipStream_t stream) {
  const float* x = (const float*)d_in[0];
  const float* f1 = (const float*)d_in[1];
  const float* b1 = (const float*)d_in[2];
  const float* f2 = (const float*)d_in[3];
  const float* b2 = (const float*)d_in[4];
  const float* fc1w = (const float*)d_in[5];
  const float* fc1b = (const float*)d_in[6];
  const float* fc2w = (const float*)d_in[7];
  const float* fc2b = (const float*)d_in[8];
  float* out = (float*)d_out;
  const int B = in_sizes[0] / 3072;  // 2048

  char* w = (char*)d_ws;
  unsigned short* Ah = (unsigned short*)w;  // B*4096 ushorts
  unsigned short* Al = (unsigned short*)(w + (size_t)B * 8192);
  unsigned short* Wh = (unsigned short*)(w + (size_t)2 * B * 8192);
  unsigned short* Wl = (unsigned short*)(w + (size_t)2 * B * 8192 + 4194304);
  float* P = (float*)(w + (size_t)2 * B * 8192 + 8388608);

  hipLaunchKernelGGL(k_conv, dim3(B + 512), dim3(256), 0, stream, x, f1, b1,
                     f2, b2, Ah, Al, fc1w, Wh, Wl, B);
  hipLaunchKernelGGL(k_fc1, dim3(1024), dim3(256), 0, stream, Ah, Al, Wh, Wl,
                     P, B);
  hipLaunchKernelGGL(k_fc2, dim3(B / 4), dim3(256), 0, stream, P, fc1b, fc2w,
                     fc2b, out, B);
}